// Round 6
// baseline (691.590 us; speedup 1.0000x reference)
//
#include <hip/hip_runtime.h>

typedef float f32x4 __attribute__((ext_vector_type(4)));
typedef __bf16 bf16x4 __attribute__((ext_vector_type(4)));
typedef __bf16 bf16x8 __attribute__((ext_vector_type(8)));
typedef short s16x4 __attribute__((ext_vector_type(4)));

#define DEVI static __device__ __forceinline__

DEVI f32x4 mfma_k32(bf16x8 a, bf16x8 b, f32x4 c) {
    return __builtin_amdgcn_mfma_f32_16x16x32_bf16(a, b, c, 0, 0, 0);
}

union B4 { bf16x4 h; s16x4 s; };
// 16x16x16 bf16 MFMA: A/B frag k-index = (lane>>4)*4+j == C/D reg layout -> lane-local refragment
DEVI f32x4 mfma_k16(bf16x4 a, bf16x4 b, f32x4 c) {
    B4 ua, ub; ua.h = a; ub.h = b;
    return __builtin_amdgcn_mfma_f32_16x16x16bf16_1k(ua.s, ub.s, c, 0, 0, 0);
}

union F8 { bf16x8 v; bf16x4 h[2]; };

DEVI bf16x8 ld8_lds(const __bf16* p) {   // 16B fragment from LDS (two b64 reads)
    F8 f;
    f.h[0] = *(const bf16x4*)p;
    f.h[1] = *(const bf16x4*)(p + 4);
    return f.v;
}
DEVI bf16x8 ld8_gb(const __bf16* p) { return *(const bf16x8*)p; }  // 16B global
DEVI bf16x4 pk4(f32x4 v) {
    bf16x4 r;
#pragma unroll
    for (int j = 0; j < 4; ++j) r[j] = (__bf16)v[j];
    return r;
}

// staging geometry: thread t < 392 handles token tok=t>>3, parts (t&7)*4 .. +3
// (part = 8 floats), i.e. 128 contiguous bytes of the token row.
DEVI size_t stage_src_off(int w, int t) {     // element offset into x
    int bb = w >> 6, wi = w & 63, wh = wi >> 3, ww = wi & 7;
    int tok = t >> 3, p0 = (t & 7) * 4;
    int i = tok / 7, j = tok - 7 * i;
    int r = wh * 7 + i + 3;  if (r >= 56) r -= 56;
    int cc = ww * 7 + j + 3; if (cc >= 56) cc -= 56;
    return (((size_t)(bb * 56 + r) * 56 + cc) << 8) + (p0 << 3);
}
DEVI int stage_dst_off(int t) {               // element offset into xw buffer
    int tok = t >> 3, p0 = (t & 7) * 4;
    return tok * 260 + p0 * 8;
}
DEVI unsigned out_base(int w, int tok) {      // element offset of token row in out
    int bb = w >> 6, wi = w & 63, wh = wi >> 3, ww = wi & 7;
    int i = tok / 7, j = tok - 7 * i;
    int r = wh * 7 + i + 3;  if (r >= 56) r -= 56;
    int cc = ww * 7 + j + 3; if (cc >= 56) cc -= 56;
    return ((unsigned)((bb * 56 + r) * 56 + cc)) << 8;
}

// ---- pre-kernel (merged):
// blocks 0..127: weights fp32 -> bf16, re-tiled into MFMA-fragment order.
//   elem = W[t*16 + (l&15)][kc*32 + (l>>4)*8 + j] -> flat ((t*8+kc)*64+l)*8+j
//   tiles 0..47 = qkv rows 0..767, tiles 48..63 = proj rows 0..255.
// blocks 128..639: bias+mask table bm[cls][h][qt][kt][lane][r] f32 (512 KB),
//   fragment-ordered: value for (q=16qt+(lane&15), key=16kt+4*(lane>>4)+r).
__global__ __launch_bounds__(256) void k_pre(const float* __restrict__ wqkv,
                                             const float* __restrict__ wp,
                                             const float* __restrict__ btab,
                                             __bf16* __restrict__ wout,
                                             float* __restrict__ bmout) {
    int bid = blockIdx.x;
    if (bid < 128) {
        int i = bid * 256 + threadIdx.x;             // one per (t,kc,l)
        int t = i >> 9, kc = (i >> 6) & 7, l = i & 63;
        int row = t * 16 + (l & 15);
        int col = kc * 32 + (l >> 4) * 8;
        const float* src = (t < 48) ? (wqkv + row * 256 + col)
                                    : (wp + (row - 768) * 256 + col);
        f32x4 a = *(const f32x4*)src;
        f32x4 b = *(const f32x4*)(src + 4);
        F8 f;
#pragma unroll
        for (int j = 0; j < 4; ++j) { f.h[0][j] = (__bf16)a[j]; f.h[1][j] = (__bf16)b[j]; }
        *(bf16x8*)(wout + (size_t)i * 8) = f.v;
    } else {
        int i = (bid - 128) * 256 + threadIdx.x;     // 0..131071
        int r = i & 3, lane = (i >> 2) & 63;
        int kt = (i >> 8) & 3, qt = (i >> 10) & 3, h = (i >> 12) & 7, cls = i >> 15;
        int li = lane & 15, g = lane >> 4;
        int q = 16 * qt + li;
        int key = 16 * kt + 4 * g + r;
        float v;
        if (key >= 49) {
            v = -30000.f;                            // pad keys: masked for all rows
        } else if (q >= 49) {
            v = 0.f;                                 // pad q rows: don't-care
        } else {
            int qi = q / 7, qj = q - 7 * qi;
            int ki = key / 7, kj = key - 7 * ki;
            float bias = btab[((qi - ki + 6) * 13 + (qj - kj + 6)) * 8 + h];
            int ch = cls >> 1, cw = cls & 1;
            int gq = (ch ? (qi < 4 ? 1 : 2) : 0) * 3 + (cw ? (qj < 4 ? 1 : 2) : 0);
            int gk = (ch ? (ki < 4 ? 1 : 2) : 0) * 3 + (cw ? (kj < 4 ? 1 : 2) : 0);
            v = bias + ((gq != gk) ? -100.f : 0.f);
        }
        bmout[i] = v;
    }
}

// ---------------------------------------------------------------------------
// Fused shifted-window attention. Persistent: 512 blocks x 4 windows each.
// 1 block = 8 waves = 8 heads. Double-buffered xw; next-window x loads issued
// before the fused phase (T14 async-STAGE), written to LDS after it.
// Softmax without max-subtraction (|s|<~10 in fp32, safe).
// ---------------------------------------------------------------------------
__global__ __launch_bounds__(512)
__attribute__((amdgpu_waves_per_eu(4))) void k_swin(
    const float* __restrict__ x,      // [32,56,56,256] fp32
    const __bf16* __restrict__ wb,    // tiled weights (ws): 64 tiles x 4096
    const float* __restrict__ bqkv,   // [768]
    const float* __restrict__ bm,     // [4][8][4][4][64][4] f32 bias+mask table
    const float* __restrict__ pbias,  // [256]
    float* __restrict__ out)          // [32,56,56,256] fp32
{
    __shared__ __align__(16) unsigned char smem[76840];
    __bf16* xw0 = (__bf16*)(smem);                // [2][49][260] staged windows
    __bf16* cb = (__bf16*)(smem + 50960);         // [49][260] ctx (attn output)
    unsigned* obase = (unsigned*)(smem + 76440);  // [2][49] output base offsets

    const int tid = threadIdx.x;
    const int wid = tid >> 6, lane = tid & 63;
    const int li = lane & 15, g = lane >> 4;
    const int h = wid;                            // wave == head
    const int pm = wid >> 2, pn = wid & 3;
    const f32x4 zf = {0.f, 0.f, 0.f, 0.f};

    const __bf16* wqb = wb + (size_t)(2 * h) * 4096 + lane * 8;  // q tiles 2h,2h+1
    const __bf16* wkb = wqb + 16 * 4096;                          // k tiles +16
    const __bf16* wvb = wqb + 32 * 4096;                          // v tiles +32
    const __bf16* wpb = wb + (size_t)(48 + 4 * pn) * 4096 + lane * 8;

    const int w0 = blockIdx.x * 4;

    // ---- initial stage: window w0 -> buffer 0 ----
    if (tid < 392) {
        f32x4 sa[4][2];
        const float* p = x + stage_src_off(w0, tid);
#pragma unroll
        for (int s = 0; s < 4; ++s) {
            sa[s][0] = *(const f32x4*)(p + s * 8);
            sa[s][1] = *(const f32x4*)(p + s * 8 + 4);
        }
        __bf16* dst = xw0 + stage_dst_off(tid);
#pragma unroll
        for (int s = 0; s < 4; ++s) {
            F8 f;
#pragma unroll
            for (int j = 0; j < 4; ++j) {
                f.h[0][j] = (__bf16)sa[s][0][j];
                f.h[1][j] = (__bf16)sa[s][1][j];
            }
            *(bf16x4*)(dst + s * 8) = f.h[0];
            *(bf16x4*)(dst + s * 8 + 4) = f.h[1];
        }
    }
    if (tid < 49) obase[tid] = out_base(w0, tid);
    __syncthreads();

    for (int it = 0; it < 4; ++it) {
        const int w = w0 + it;
        const int wi = w & 63;
        const int cls = (((wi >> 3) == 7) ? 2 : 0) + (((wi & 7) == 7) ? 1 : 0);
        const int cur = it & 1, nxt = cur ^ 1;
        const __bf16* xwc = xw0 + cur * 12740;

        // ---- Phase 1: Q,K GEMM (acc[ct][tt]: ch=16ct+4g+r, tok=16tt+li) ----
        bf16x4 qf[4][2], kf[4][2];   // frags: row=li=tok, k=4g+j=ch(16ct+4g+j)
        {
            f32x4 qa[2][4], ka[2][4];
#pragma unroll
            for (int ct = 0; ct < 2; ++ct)
#pragma unroll
                for (int tt = 0; tt < 4; ++tt) { qa[ct][tt] = zf; ka[ct][tt] = zf; }

#pragma unroll
            for (int kc = 0; kc < 8; ++kc) {
                bf16x8 xf[4];
#pragma unroll
                for (int tt = 0; tt < 4; ++tt) {
                    int row = 16 * tt + li; if (row > 48) row = 48;   // clamp pads
                    xf[tt] = ld8_lds(xwc + row * 260 + kc * 32 + g * 8);
                }
#pragma unroll
                for (int ct = 0; ct < 2; ++ct) {
                    bf16x8 aq = ld8_gb(wqb + ct * 4096 + kc * 512);
                    bf16x8 ak = ld8_gb(wkb + ct * 4096 + kc * 512);
#pragma unroll
                    for (int tt = 0; tt < 4; ++tt) {
                        qa[ct][tt] = mfma_k32(aq, xf[tt], qa[ct][tt]);
                        ka[ct][tt] = mfma_k32(ak, xf[tt], ka[ct][tt]);
                    }
                }
            }
#pragma unroll
            for (int ct = 0; ct < 2; ++ct) {
                f32x4 bq = *(const f32x4*)(bqkv + h * 32 + 16 * ct + 4 * g);
                f32x4 bk = *(const f32x4*)(bqkv + 256 + h * 32 + 16 * ct + 4 * g);
#pragma unroll
                for (int tt = 0; tt < 4; ++tt)
#pragma unroll
                    for (int r = 0; r < 4; ++r) {
                        qf[tt][ct][r] = (__bf16)((qa[ct][tt][r] + bq[r]) * 0.17677669529663687f);
                        kf[tt][ct][r] = (__bf16)(ka[ct][tt][r] + bk[r]);
                    }
            }
        }
        __builtin_amdgcn_sched_barrier(0);   // qa/ka dead before va allocates

        // ---- Phase 2: V GEMM (acc[tt][ct]: tok=16tt+4g+r, ch=16ct+li) ----
        bf16x4 vf[2][4];   // V^T frags [dt][kt]: row=li=d, k=4g+j=key
        {
            f32x4 va[4][2];
#pragma unroll
            for (int tt = 0; tt < 4; ++tt)
#pragma unroll
                for (int ct = 0; ct < 2; ++ct) va[tt][ct] = zf;
#pragma unroll
            for (int kc = 0; kc < 8; ++kc) {
                bf16x8 bv0 = ld8_gb(wvb + kc * 512);
                bf16x8 bv1 = ld8_gb(wvb + 4096 + kc * 512);
#pragma unroll
                for (int tt = 0; tt < 4; ++tt) {
                    int row = 16 * tt + li; if (row > 48) row = 48;
                    bf16x8 xf = ld8_lds(xwc + row * 260 + kc * 32 + g * 8);
                    va[tt][0] = mfma_k32(xf, bv0, va[tt][0]);
                    va[tt][1] = mfma_k32(xf, bv1, va[tt][1]);
                }
            }
#pragma unroll
            for (int ct = 0; ct < 2; ++ct) {
                float bv = bqkv[512 + h * 32 + 16 * ct + li];
#pragma unroll
                for (int tt = 0; tt < 4; ++tt)
#pragma unroll
                    for (int r = 0; r < 4; ++r)
                        vf[ct][tt][r] = (__bf16)(va[tt][ct][r] + bv);
            }
        }
        __builtin_amdgcn_sched_barrier(0);   // va dead before fused loop

        // ---- issue next-window staging loads (consumed after fused phase) ----
        const bool hn = (it < 3);
        f32x4 sa[4][2];
        if (hn && tid < 392) {
            const float* p = x + stage_src_off(w + 1, tid);
#pragma unroll
            for (int s = 0; s < 4; ++s) {
                sa[s][0] = *(const f32x4*)(p + s * 8);
                sa[s][1] = *(const f32x4*)(p + s * 8 + 4);
            }
        }

        // ---- Phase 3: fused per-qt {S, softmax(no max-sub), PV, ctx scatter} ----
        const float* bmq = bm + cls * 32768 + h * 4096 + lane * 4;
#pragma unroll
        for (int qt = 0; qt < 4; ++qt) {
            f32x4 sv[4];   // S^T frags: lane holds key=16kt+4g+r, q=16qt+li
#pragma unroll
            for (int kt = 0; kt < 4; ++kt) {
                f32x4 acc = zf;
                acc = mfma_k16(kf[kt][0], qf[qt][0], acc);
                acc = mfma_k16(kf[kt][1], qf[qt][1], acc);
                sv[kt] = acc + *(const f32x4*)(bmq + qt * 1024 + kt * 256);
            }
            float sum = 0.f;
#pragma unroll
            for (int kt = 0; kt < 4; ++kt)
#pragma unroll
                for (int r = 0; r < 4; ++r) {
                    float e = __expf(sv[kt][r]);
                    sv[kt][r] = e;
                    sum += e;
                }
            sum += __shfl_xor(sum, 16);
            sum += __shfl_xor(sum, 32);
            float inv = 1.0f / sum;
            bf16x4 pp[4];  // P frags: row=li=q, k=4g+j=key
#pragma unroll
            for (int kt = 0; kt < 4; ++kt)
#pragma unroll
                for (int r = 0; r < 4; ++r) pp[kt][r] = (__bf16)(sv[kt][r] * inv);
#pragma unroll
            for (int dt = 0; dt < 2; ++dt) {
                f32x4 acc = zf;
#pragma unroll
                for (int kt = 0; kt < 4; ++kt)
                    acc = mfma_k16(pp[kt], vf[dt][kt], acc);
                bf16x4 o4 = pk4(acc);
#pragma unroll
                for (int r = 0; r < 4; ++r) {
                    int q = 16 * qt + 4 * g + r;
                    if (q < 49) cb[q * 260 + 32 * h + 16 * dt + li] = o4[r];
                }
            }
        }

        // ---- staging writes for next window (loads landed under fused phase) ----
        if (hn && tid < 392) {
            __bf16* dst = xw0 + nxt * 12740 + stage_dst_off(tid);
#pragma unroll
            for (int s = 0; s < 4; ++s) {
                F8 f;
#pragma unroll
                for (int j = 0; j < 4; ++j) {
                    f.h[0][j] = (__bf16)sa[s][0][j];
                    f.h[1][j] = (__bf16)sa[s][1][j];
                }
                *(bf16x4*)(dst + s * 8) = f.h[0];
                *(bf16x4*)(dst + s * 8 + 4) = f.h[1];
            }
        }
        if (hn && tid < 49) obase[nxt * 49 + tid] = out_base(w + 1, tid);
        __syncthreads();   // B1: cb + next-window xw/obase complete

        // ---- proj: 8 waves, wave = (pm: 32 rows, pn: 64 cols) ----
        f32x4 pacc[2][4];
#pragma unroll
        for (int mt = 0; mt < 2; ++mt)
#pragma unroll
            for (int nt = 0; nt < 4; ++nt) pacc[mt][nt] = zf;

#pragma unroll
        for (int kc = 0; kc < 8; ++kc) {
            bf16x8 a[2];
#pragma unroll
            for (int mt = 0; mt < 2; ++mt) {
                int row = 32 * pm + 16 * mt + li; if (row > 48) row = 48;
                a[mt] = ld8_lds(cb + row * 260 + kc * 32 + g * 8);
            }
#pragma unroll
            for (int nt = 0; nt < 4; ++nt) {
                bf16x8 bb = ld8_gb(wpb + nt * 4096 + kc * 512);
#pragma unroll
                for (int mt = 0; mt < 2; ++mt)
                    pacc[mt][nt] = mfma_k32(a[mt], bb, pacc[mt][nt]);
            }
        }

        // ---- epilogue: bias + direct fp32 scatter via obase LUT ----
#pragma unroll
        for (int nt = 0; nt < 4; ++nt) {
            int o = 64 * pn + 16 * nt + li;
            float bias = pbias[o];
#pragma unroll
            for (int mt = 0; mt < 2; ++mt)
#pragma unroll
                for (int r = 0; r < 4; ++r) {
                    int n = 32 * pm + 16 * mt + 4 * g + r;
                    if (n < 49)
                        out[obase[cur * 49 + n] + (unsigned)o] = pacc[mt][nt][r] + bias;
                }
        }
        __syncthreads();   // B2: proj reads of cb/obase done before next overwrite
    }
}

extern "C" void kernel_launch(void* const* d_in, const int* in_sizes, int n_in,
                              void* d_out, int out_size, void* d_ws, size_t ws_size,
                              hipStream_t stream) {
    const float* x    = (const float*)d_in[0];
    const float* wqkv = (const float*)d_in[1];
    const float* bqkv = (const float*)d_in[2];
    const float* wp   = (const float*)d_in[3];
    const float* pb   = (const float*)d_in[4];
    const float* btab = (const float*)d_in[5];
    float* out = (float*)d_out;

    __bf16* wbuf = (__bf16*)d_ws;                       // 512 KB weights (bf16)
    float* bm = (float*)((char*)d_ws + 524288);         // 512 KB bias+mask table
    k_pre<<<640, 256, 0, stream>>>(wqkv, wp, btab, wbuf, bm);
    k_swin<<<512, 512, 0, stream>>>(x, wbuf, bqkv, bm, pb, out);
}

// Round 8
// 269.403 us; speedup vs baseline: 2.5671x; 2.5671x over previous
//
#include <hip/hip_runtime.h>

typedef float f32x4 __attribute__((ext_vector_type(4)));
typedef __bf16 bf16x4 __attribute__((ext_vector_type(4)));
typedef __bf16 bf16x8 __attribute__((ext_vector_type(8)));
typedef short s16x4 __attribute__((ext_vector_type(4)));

#define DEVI static __device__ __forceinline__

#define LOG2E 1.4426950408889634f
#define QSCALE (0.17677669529663687f * 1.4426950408889634f)

DEVI f32x4 mfma_k32(bf16x8 a, bf16x8 b, f32x4 c) {
    return __builtin_amdgcn_mfma_f32_16x16x32_bf16(a, b, c, 0, 0, 0);
}

union B4 { bf16x4 h; s16x4 s; };
// 16x16x16 bf16 MFMA: A/B frag k-index = (lane>>4)*4+j == C/D reg layout -> lane-local refragment
DEVI f32x4 mfma_k16(bf16x4 a, bf16x4 b, f32x4 c) {
    B4 ua, ub; ua.h = a; ub.h = b;
    return __builtin_amdgcn_mfma_f32_16x16x16bf16_1k(ua.s, ub.s, c, 0, 0, 0);
}

// TRANS ops via builtins (NOT inline asm): v_exp/v_rcp results need a HW wait
// state; the compiler inserts it for intrinsics but cannot see inside asm().
DEVI float exp2_hw(float x) { return __builtin_amdgcn_exp2f(x); }
DEVI float rcp_hw(float x)  { return __builtin_amdgcn_rcpf(x); }

union F8 { bf16x8 v; bf16x4 h[2]; };

DEVI bf16x8 ld8_lds(const __bf16* p) {   // 16B fragment from LDS (two b64 reads)
    F8 f;
    f.h[0] = *(const bf16x4*)p;
    f.h[1] = *(const bf16x4*)(p + 4);
    return f.v;
}
DEVI bf16x8 ld8_gb(const __bf16* p) { return *(const bf16x8*)p; }  // 16B global
DEVI bf16x8 ldf8(const float* p) {       // 8 fp32 -> bf16x8
    f32x4 a = *(const f32x4*)p;
    f32x4 b = *(const f32x4*)(p + 4);
    F8 f;
#pragma unroll
    for (int j = 0; j < 4; ++j) {
        f.h[0][j] = (__bf16)a[j];
        f.h[1][j] = (__bf16)b[j];
    }
    return f.v;
}
DEVI bf16x4 pk4(f32x4 v) {
    bf16x4 r;
#pragma unroll
    for (int j = 0; j < 4; ++j) r[j] = (__bf16)v[j];
    return r;
}

// ---- pre-kernel (merged):
// blocks 0..127: weights fp32 -> bf16, re-tiled into MFMA-fragment order.
//   elem = W[t*16 + (l&15)][kc*32 + (l>>4)*8 + j] -> flat ((t*8+kc)*64+l)*8+j
//   tiles 0..47 = qkv rows 0..767 (Q tiles 0..15 pre-scaled by QSCALE),
//   tiles 48..63 = proj rows 0..255.
// blocks 128..639: bias+mask table bm[cls][h][qt][kt][lane][r] f32 (512 KB),
//   fragment-ordered, pre-scaled by LOG2E (softmax runs in exp2 domain).
__global__ __launch_bounds__(256) void k_pre(const float* __restrict__ wqkv,
                                             const float* __restrict__ wp,
                                             const float* __restrict__ btab,
                                             __bf16* __restrict__ wout,
                                             float* __restrict__ bmout) {
    int bid = blockIdx.x;
    if (bid < 128) {
        int i = bid * 256 + threadIdx.x;             // one per (t,kc,l)
        int t = i >> 9, kc = (i >> 6) & 7, l = i & 63;
        int row = t * 16 + (l & 15);
        int col = kc * 32 + (l >> 4) * 8;
        const float* src = (t < 48) ? (wqkv + row * 256 + col)
                                    : (wp + (row - 768) * 256 + col);
        float s = (t < 16) ? QSCALE : 1.0f;          // fold q-scale*log2e into Wq
        f32x4 a = *(const f32x4*)src;
        f32x4 b = *(const f32x4*)(src + 4);
        F8 f;
#pragma unroll
        for (int j = 0; j < 4; ++j) {
            f.h[0][j] = (__bf16)(a[j] * s);
            f.h[1][j] = (__bf16)(b[j] * s);
        }
        *(bf16x8*)(wout + (size_t)i * 8) = f.v;
    } else {
        int i = (bid - 128) * 256 + threadIdx.x;     // 0..131071
        int r = i & 3, lane = (i >> 2) & 63;
        int kt = (i >> 8) & 3, qt = (i >> 10) & 3, h = (i >> 12) & 7, cls = i >> 15;
        int li = lane & 15, g = lane >> 4;
        int q = 16 * qt + li;
        int key = 16 * kt + 4 * g + r;
        float v;
        if (key >= 49) {
            v = -30000.f;                            // pad keys: masked for all rows
        } else if (q >= 49) {
            v = 0.f;                                 // pad q rows: don't-care
        } else {
            int qi = q / 7, qj = q - 7 * qi;
            int ki = key / 7, kj = key - 7 * ki;
            float bias = btab[((qi - ki + 6) * 13 + (qj - kj + 6)) * 8 + h];
            int ch = cls >> 1, cw = cls & 1;
            int gq = (ch ? (qi < 4 ? 1 : 2) : 0) * 3 + (cw ? (qj < 4 ? 1 : 2) : 0);
            int gk = (ch ? (ki < 4 ? 1 : 2) : 0) * 3 + (cw ? (kj < 4 ? 1 : 2) : 0);
            v = bias + ((gq != gk) ? -100.f : 0.f);
        }
        bmout[i] = v * LOG2E;                        // exp2-domain softmax
    }
}

// ---------------------------------------------------------------------------
// Fused shifted-window attention. 1 block = 1 window, 8 waves = 8 heads.
// 2 barriers; attention register-resident; phase order QK -> V -> fused
// per-qt {S, exp2-softmax (no max-sub), PV}. All MFMA accumulators are
// bias-initialized; PV/proj operand-swapped for vectorized stores.
// ---------------------------------------------------------------------------
__global__ __launch_bounds__(512)
__attribute__((amdgpu_waves_per_eu(4))) void k_swin(
    const float* __restrict__ x,      // [32,56,56,256] fp32
    const __bf16* __restrict__ wb,    // tiled weights (ws): 64 tiles x 4096
    const float* __restrict__ bqkv,   // [768]
    const float* __restrict__ bm,     // [4][8][4][4][64][4] f32 bias+mask (log2e)
    const float* __restrict__ pbias,  // [256]
    float* __restrict__ out)          // [32,56,56,256] fp32
{
    __shared__ __align__(16) unsigned char smem[51216];
    __bf16* xw = (__bf16*)(smem);                 // [49][260] staged window (bf16)
    __bf16* cb = (__bf16*)(smem + 25480);         // [49][260] ctx (attn output)
    unsigned* obase = (unsigned*)(smem + 50960);  // [49] output base offsets

    const int tid = threadIdx.x;
    const int wid = tid >> 6, lane = tid & 63;
    const int li = lane & 15, g = lane >> 4;
    const int blk = blockIdx.x;
    const int b = blk >> 6, wi = blk & 63;
    const int wh = wi >> 3, ww = wi & 7;
    const int h = wid;                            // wave == head
    const int cls = ((wh == 7) ? 2 : 0) + ((ww == 7) ? 1 : 0);

    // ---- stage shifted window (fp32 -> bf16) ----
    for (int c = tid; c < 49 * 32; c += 512) {
        int tok = c >> 5, part = c & 31;
        int i = tok / 7, j = tok - 7 * i;
        int r = wh * 7 + i + 3;  if (r >= 56) r -= 56;
        int cc = ww * 7 + j + 3; if (cc >= 56) cc -= 56;
        F8 f; f.v = ldf8(x + (((size_t)(b * 56 + r) * 56 + cc) << 8) + (part << 3));
        __bf16* dst = xw + tok * 260 + (part << 3);
        *(bf16x4*)dst = f.h[0];
        *(bf16x4*)(dst + 4) = f.h[1];
    }
    if (tid < 49) {                                  // output base addresses
        int i = tid / 7, j = tid - 7 * i;
        int r = wh * 7 + i + 3;  if (r >= 56) r -= 56;
        int cc = ww * 7 + j + 3; if (cc >= 56) cc -= 56;
        obase[tid] = ((unsigned)((b * 56 + r) * 56 + cc)) << 8;
    }
    __syncthreads();   // barrier #1 (xw/obase ready; read-only afterwards)

    const f32x4 zf = {0.f, 0.f, 0.f, 0.f};
    const __bf16* wqb = wb + (size_t)(2 * h) * 4096 + lane * 8;  // q tiles 2h,2h+1
    const __bf16* wkb = wqb + 16 * 4096;                          // k tiles +16
    const __bf16* wvb = wqb + 32 * 4096;                          // v tiles +32

    // ---- Phase 1: Q,K GEMM (acc[ct][tt]: ch=16ct+4g+r, tok=16tt+li) ----
    bf16x4 qf[4][2], kf[4][2];   // frags: row=li=tok, k=4g+j=ch(16ct+4g+j)
    {
        f32x4 bq[2], bk[2];      // bias-init values (q pre-scaled weights -> scale bias too)
#pragma unroll
        for (int ct = 0; ct < 2; ++ct) {
            bq[ct] = *(const f32x4*)(bqkv + h * 32 + 16 * ct + 4 * g) * QSCALE;
            bk[ct] = *(const f32x4*)(bqkv + 256 + h * 32 + 16 * ct + 4 * g);
        }
        f32x4 qa[2][4], ka[2][4];
#pragma unroll
        for (int ct = 0; ct < 2; ++ct)
#pragma unroll
            for (int tt = 0; tt < 4; ++tt) { qa[ct][tt] = bq[ct]; ka[ct][tt] = bk[ct]; }

#pragma unroll
        for (int kc = 0; kc < 8; ++kc) {
            bf16x8 xf[4];
#pragma unroll
            for (int tt = 0; tt < 4; ++tt) {
                int row = 16 * tt + li; if (row > 48) row = 48;   // clamp pad rows
                xf[tt] = ld8_lds(xw + row * 260 + kc * 32 + g * 8);
            }
#pragma unroll
            for (int ct = 0; ct < 2; ++ct) {
                bf16x8 aq = ld8_gb(wqb + ct * 4096 + kc * 512);
                bf16x8 ak = ld8_gb(wkb + ct * 4096 + kc * 512);
#pragma unroll
                for (int tt = 0; tt < 4; ++tt) {
                    qa[ct][tt] = mfma_k32(aq, xf[tt], qa[ct][tt]);
                    ka[ct][tt] = mfma_k32(ak, xf[tt], ka[ct][tt]);
                }
            }
        }
        // lane-local refragment (pure cvt; bias already in)
#pragma unroll
        for (int ct = 0; ct < 2; ++ct)
#pragma unroll
            for (int tt = 0; tt < 4; ++tt)
#pragma unroll
                for (int r = 0; r < 4; ++r) {
                    qf[tt][ct][r] = (__bf16)qa[ct][tt][r];
                    kf[tt][ct][r] = (__bf16)ka[ct][tt][r];
                }
    }
    __builtin_amdgcn_sched_barrier(0);   // qa/ka dead before va allocates

    // ---- Phase 2: V GEMM (acc[tt][ct]: tok=16tt+4g+r, ch=16ct+li) ----
    bf16x4 vf[2][4];   // V^T frags [dt][kt]: row=li=d, k=4g+j=key
    {
        float bv0 = bqkv[512 + h * 32 + li];
        float bv1 = bqkv[512 + h * 32 + 16 + li];
        f32x4 va[4][2];
#pragma unroll
        for (int tt = 0; tt < 4; ++tt) {
            va[tt][0] = (f32x4){bv0, bv0, bv0, bv0};
            va[tt][1] = (f32x4){bv1, bv1, bv1, bv1};
        }
#pragma unroll
        for (int kc = 0; kc < 8; ++kc) {
            bf16x8 bvw0 = ld8_gb(wvb + kc * 512);
            bf16x8 bvw1 = ld8_gb(wvb + 4096 + kc * 512);
#pragma unroll
            for (int tt = 0; tt < 4; ++tt) {
                int row = 16 * tt + li; if (row > 48) row = 48;
                bf16x8 xf = ld8_lds(xw + row * 260 + kc * 32 + g * 8);
                va[tt][0] = mfma_k32(xf, bvw0, va[tt][0]);
                va[tt][1] = mfma_k32(xf, bvw1, va[tt][1]);
            }
        }
#pragma unroll
        for (int ct = 0; ct < 2; ++ct)
#pragma unroll
            for (int tt = 0; tt < 4; ++tt)
#pragma unroll
                for (int r = 0; r < 4; ++r)
                    vf[ct][tt][r] = (__bf16)va[tt][ct][r];
    }
    __builtin_amdgcn_sched_barrier(0);   // va dead before fused loop

    // ---- Phase 3: fused per-qt {S, exp2-softmax, PV, vector ctx store} ----
    const float* bmq = bm + cls * 32768 + h * 4096 + lane * 4;
#pragma unroll
    for (int qt = 0; qt < 4; ++qt) {
        f32x4 sv[4];   // S^T frags: lane holds key=16kt+4g+r, q=16qt+li
#pragma unroll
        for (int kt = 0; kt < 4; ++kt) {
            f32x4 acc = *(const f32x4*)(bmq + qt * 1024 + kt * 256);  // bias+mask (log2e)
            acc = mfma_k16(kf[kt][0], qf[qt][0], acc);
            acc = mfma_k16(kf[kt][1], qf[qt][1], acc);
            sv[kt] = acc;
        }
        float sum = 0.f;
#pragma unroll
        for (int kt = 0; kt < 4; ++kt)
#pragma unroll
            for (int r = 0; r < 4; ++r) {
                float e = exp2_hw(sv[kt][r]);   // no max-sub: |sv|<~25, masked -> 0
                sv[kt][r] = e;
                sum += e;
            }
        sum += __shfl_xor(sum, 16);
        sum += __shfl_xor(sum, 32);
        float inv = rcp_hw(sum);
        bf16x4 pp[4];  // unnormalized P frags: row=li=q, k=4g+j=key
#pragma unroll
        for (int kt = 0; kt < 4; ++kt)
#pragma unroll
            for (int r = 0; r < 4; ++r) pp[kt][r] = (__bf16)sv[kt][r];
        // PV swapped: A=vf -> d on 4g+r, B=pp -> q on li; inv is lane-local (q=li)
        const int q = 16 * qt + li;
#pragma unroll
        for (int dt = 0; dt < 2; ++dt) {
            f32x4 acc = zf;
#pragma unroll
            for (int kt = 0; kt < 4; ++kt)
                acc = mfma_k16(vf[dt][kt], pp[kt], acc);
            acc *= inv;
            bf16x4 o4 = pk4(acc);
            if (q < 49)
                *(bf16x4*)(cb + q * 260 + 32 * h + 16 * dt + 4 * g) = o4;
        }
    }
    __syncthreads();   // barrier #2 (ctx complete)

    // ---- proj: 8 waves, wave = (pm: 32 rows, pn: 64 cols) ----
    // swapped: A=wp rows -> o on 4g+r, B=cb rows -> tok on li
    const int pm = wid >> 2, pn = wid & 3;
    const __bf16* wpb = wb + (size_t)(48 + 4 * pn) * 4096 + lane * 8;

    f32x4 pb4[4];
#pragma unroll
    for (int nt = 0; nt < 4; ++nt)
        pb4[nt] = *(const f32x4*)(pbias + 64 * pn + 16 * nt + 4 * g);
    f32x4 pacc[2][4];
#pragma unroll
    for (int mt = 0; mt < 2; ++mt)
#pragma unroll
        for (int nt = 0; nt < 4; ++nt) pacc[mt][nt] = pb4[nt];

#pragma unroll
    for (int kc = 0; kc < 8; ++kc) {
        bf16x8 a[2];
#pragma unroll
        for (int mt = 0; mt < 2; ++mt) {
            int row = 32 * pm + 16 * mt + li; if (row > 48) row = 48;
            a[mt] = ld8_lds(cb + row * 260 + kc * 32 + g * 8);
        }
#pragma unroll
        for (int nt = 0; nt < 4; ++nt) {
            bf16x8 bb = ld8_gb(wpb + nt * 4096 + kc * 512);
#pragma unroll
            for (int mt = 0; mt < 2; ++mt)
                pacc[mt][nt] = mfma_k32(bb, a[mt], pacc[mt][nt]);
        }
    }

    // ---- epilogue: vector fp32 scatter via obase LUT (bias pre-initialized) ----
#pragma unroll
    for (int mt = 0; mt < 2; ++mt) {
        int tok = 32 * pm + 16 * mt + li;
        if (tok < 49) {
            float* op = out + obase[tok] + 64 * pn + 4 * g;
#pragma unroll
            for (int nt = 0; nt < 4; ++nt)
                *(f32x4*)(op + 16 * nt) = pacc[mt][nt];
        }
    }
}

extern "C" void kernel_launch(void* const* d_in, const int* in_sizes, int n_in,
                              void* d_out, int out_size, void* d_ws, size_t ws_size,
                              hipStream_t stream) {
    const float* x    = (const float*)d_in[0];
    const float* wqkv = (const float*)d_in[1];
    const float* bqkv = (const float*)d_in[2];
    const float* wp   = (const float*)d_in[3];
    const float* pb   = (const float*)d_in[4];
    const float* btab = (const float*)d_in[5];
    float* out = (float*)d_out;

    __bf16* wbuf = (__bf16*)d_ws;                       // 512 KB weights (bf16)
    float* bm = (float*)((char*)d_ws + 524288);         // 512 KB bias+mask table
    k_pre<<<640, 256, 0, stream>>>(wqkv, wp, btab, wbuf, bm);
    k_swin<<<2048, 512, 0, stream>>>(x, wbuf, bqkv, bm, pb, out);
}

// Round 9
// 265.125 us; speedup vs baseline: 2.6085x; 1.0161x over previous
//
#include <hip/hip_runtime.h>

typedef float f32x4 __attribute__((ext_vector_type(4)));
typedef __bf16 bf16x4 __attribute__((ext_vector_type(4)));
typedef __bf16 bf16x8 __attribute__((ext_vector_type(8)));
typedef short s16x4 __attribute__((ext_vector_type(4)));

#define DEVI static __device__ __forceinline__

#define LOG2E 1.4426950408889634f
#define QSCALE (0.17677669529663687f * 1.4426950408889634f)

DEVI f32x4 mfma_k32(bf16x8 a, bf16x8 b, f32x4 c) {
    return __builtin_amdgcn_mfma_f32_16x16x32_bf16(a, b, c, 0, 0, 0);
}

union B4 { bf16x4 h; s16x4 s; };
// 16x16x16 bf16 MFMA: A/B frag k-index = (lane>>4)*4+j == C/D reg layout -> lane-local refragment
DEVI f32x4 mfma_k16(bf16x4 a, bf16x4 b, f32x4 c) {
    B4 ua, ub; ua.h = a; ub.h = b;
    return __builtin_amdgcn_mfma_f32_16x16x16bf16_1k(ua.s, ub.s, c, 0, 0, 0);
}

// TRANS ops via builtins (NOT inline asm): v_exp/v_rcp results need a HW wait
// state; the compiler inserts it for intrinsics but cannot see inside asm().
DEVI float exp2_hw(float x) { return __builtin_amdgcn_exp2f(x); }
DEVI float rcp_hw(float x)  { return __builtin_amdgcn_rcpf(x); }

union F8 { bf16x8 v; bf16x4 h[2]; };

DEVI bf16x8 ld8_lds(const __bf16* p) {   // 16B fragment from LDS (two b64 reads)
    F8 f;
    f.h[0] = *(const bf16x4*)p;
    f.h[1] = *(const bf16x4*)(p + 4);
    return f.v;
}
DEVI bf16x8 ld8_gb(const __bf16* p) { return *(const bf16x8*)p; }  // 16B global
DEVI bf16x8 ldf8(const float* p) {       // 8 fp32 -> bf16x8
    f32x4 a = *(const f32x4*)p;
    f32x4 b = *(const f32x4*)(p + 4);
    F8 f;
#pragma unroll
    for (int j = 0; j < 4; ++j) {
        f.h[0][j] = (__bf16)a[j];
        f.h[1][j] = (__bf16)b[j];
    }
    return f.v;
}
DEVI bf16x4 pk4(f32x4 v) {
    bf16x4 r;
#pragma unroll
    for (int j = 0; j < 4; ++j) r[j] = (__bf16)v[j];
    return r;
}

// ---- pre-kernel (merged):
// blocks 0..127: weights fp32 -> bf16, re-tiled into MFMA-fragment order.
//   elem = W[t*16 + (l&15)][kc*32 + (l>>4)*8 + j] -> flat ((t*8+kc)*64+l)*8+j
//   tiles 0..47 = qkv rows 0..767 (Q tiles 0..15 pre-scaled by QSCALE),
//   tiles 48..63 = proj rows 0..255.
// blocks 128..639: bias+mask table bm[cls][h][qt][kt][lane][r] f32 (512 KB),
//   fragment-ordered, pre-scaled by LOG2E (softmax runs in exp2 domain).
__global__ __launch_bounds__(256) void k_pre(const float* __restrict__ wqkv,
                                             const float* __restrict__ wp,
                                             const float* __restrict__ btab,
                                             __bf16* __restrict__ wout,
                                             float* __restrict__ bmout) {
    int bid = blockIdx.x;
    if (bid < 128) {
        int i = bid * 256 + threadIdx.x;             // one per (t,kc,l)
        int t = i >> 9, kc = (i >> 6) & 7, l = i & 63;
        int row = t * 16 + (l & 15);
        int col = kc * 32 + (l >> 4) * 8;
        const float* src = (t < 48) ? (wqkv + row * 256 + col)
                                    : (wp + (row - 768) * 256 + col);
        float s = (t < 16) ? QSCALE : 1.0f;          // fold q-scale*log2e into Wq
        f32x4 a = *(const f32x4*)src;
        f32x4 b = *(const f32x4*)(src + 4);
        F8 f;
#pragma unroll
        for (int j = 0; j < 4; ++j) {
            f.h[0][j] = (__bf16)(a[j] * s);
            f.h[1][j] = (__bf16)(b[j] * s);
        }
        *(bf16x8*)(wout + (size_t)i * 8) = f.v;
    } else {
        int i = (bid - 128) * 256 + threadIdx.x;     // 0..131071
        int r = i & 3, lane = (i >> 2) & 63;
        int kt = (i >> 8) & 3, qt = (i >> 10) & 3, h = (i >> 12) & 7, cls = i >> 15;
        int li = lane & 15, g = lane >> 4;
        int q = 16 * qt + li;
        int key = 16 * kt + 4 * g + r;
        float v;
        if (key >= 49) {
            v = -30000.f;                            // pad keys: masked for all rows
        } else if (q >= 49) {
            v = 0.f;                                 // pad q rows: don't-care
        } else {
            int qi = q / 7, qj = q - 7 * qi;
            int ki = key / 7, kj = key - 7 * ki;
            float bias = btab[((qi - ki + 6) * 13 + (qj - kj + 6)) * 8 + h];
            int ch = cls >> 1, cw = cls & 1;
            int gq = (ch ? (qi < 4 ? 1 : 2) : 0) * 3 + (cw ? (qj < 4 ? 1 : 2) : 0);
            int gk = (ch ? (ki < 4 ? 1 : 2) : 0) * 3 + (cw ? (kj < 4 ? 1 : 2) : 0);
            v = bias + ((gq != gk) ? -100.f : 0.f);
        }
        bmout[i] = v * LOG2E;                        // exp2-domain softmax
    }
}

// ---------------------------------------------------------------------------
// Fused shifted-window attention. 1 block = 1 window, 8 waves = 8 heads.
// 2 barriers; attention register-resident. Phases Q -> K -> V -> fused
// per-qt {S, exp2-softmax, PV} -> proj. Each GEMM phase reuses one 32-reg
// accumulator block (peak live ~70-85 regs -> no spill at the 128 cap).
// ---------------------------------------------------------------------------
__global__ __launch_bounds__(512)
__attribute__((amdgpu_waves_per_eu(4))) void k_swin(
    const float* __restrict__ x,      // [32,56,56,256] fp32
    const __bf16* __restrict__ wb,    // tiled weights (ws): 64 tiles x 4096
    const float* __restrict__ bqkv,   // [768]
    const float* __restrict__ bm,     // [4][8][4][4][64][4] f32 bias+mask (log2e)
    const float* __restrict__ pbias,  // [256]
    float* __restrict__ out)          // [32,56,56,256] fp32
{
    __shared__ __align__(16) unsigned char smem[51216];
    __bf16* xw = (__bf16*)(smem);                 // [49][260] staged window (bf16)
    __bf16* cb = (__bf16*)(smem + 25480);         // [49][260] ctx (attn output)
    unsigned* obase = (unsigned*)(smem + 50960);  // [49] output base offsets

    const int tid = threadIdx.x;
    const int wid = tid >> 6, lane = tid & 63;
    const int li = lane & 15, g = lane >> 4;
    const int blk = blockIdx.x;
    const int b = blk >> 6, wi = blk & 63;
    const int wh = wi >> 3, ww = wi & 7;
    const int h = wid;                            // wave == head
    const int cls = ((wh == 7) ? 2 : 0) + ((ww == 7) ? 1 : 0);

    // ---- stage shifted window (fp32 -> bf16) ----
    for (int c = tid; c < 49 * 32; c += 512) {
        int tok = c >> 5, part = c & 31;
        int i = tok / 7, j = tok - 7 * i;
        int r = wh * 7 + i + 3;  if (r >= 56) r -= 56;
        int cc = ww * 7 + j + 3; if (cc >= 56) cc -= 56;
        F8 f; f.v = ldf8(x + (((size_t)(b * 56 + r) * 56 + cc) << 8) + (part << 3));
        __bf16* dst = xw + tok * 260 + (part << 3);
        *(bf16x4*)dst = f.h[0];
        *(bf16x4*)(dst + 4) = f.h[1];
    }
    if (tid < 49) {                                  // output base addresses
        int i = tid / 7, j = tid - 7 * i;
        int r = wh * 7 + i + 3;  if (r >= 56) r -= 56;
        int cc = ww * 7 + j + 3; if (cc >= 56) cc -= 56;
        obase[tid] = ((unsigned)((b * 56 + r) * 56 + cc)) << 8;
    }
    __syncthreads();   // barrier #1 (xw/obase ready; read-only afterwards)

    const f32x4 zf = {0.f, 0.f, 0.f, 0.f};
    const __bf16* wqb = wb + (size_t)(2 * h) * 4096 + lane * 8;  // q tiles 2h,2h+1
    const __bf16* wkb = wqb + 16 * 4096;                          // k tiles +16
    const __bf16* wvb = wqb + 32 * 4096;                          // v tiles +32

    bf16x4 qf[4][2], kf[4][2];   // frags: row=li=tok, k=4g+j=ch(16ct+4g+j)

    // ---- Phase 1a: Q GEMM (acc[ct][tt]: ch=16ct+4g+r, tok=16tt+li) ----
    {
        f32x4 acc[2][4];
#pragma unroll
        for (int ct = 0; ct < 2; ++ct) {
            f32x4 bq = *(const f32x4*)(bqkv + h * 32 + 16 * ct + 4 * g) * QSCALE;
#pragma unroll
            for (int tt = 0; tt < 4; ++tt) acc[ct][tt] = bq;
        }
#pragma unroll
        for (int kc = 0; kc < 8; ++kc) {
            bf16x8 xf[4];
#pragma unroll
            for (int tt = 0; tt < 4; ++tt) {
                int row = 16 * tt + li; if (row > 48) row = 48;   // clamp pad rows
                xf[tt] = ld8_lds(xw + row * 260 + kc * 32 + g * 8);
            }
#pragma unroll
            for (int ct = 0; ct < 2; ++ct) {
                bf16x8 aq = ld8_gb(wqb + ct * 4096 + kc * 512);
#pragma unroll
                for (int tt = 0; tt < 4; ++tt)
                    acc[ct][tt] = mfma_k32(aq, xf[tt], acc[ct][tt]);
            }
        }
#pragma unroll
        for (int ct = 0; ct < 2; ++ct)
#pragma unroll
            for (int tt = 0; tt < 4; ++tt)
#pragma unroll
                for (int r = 0; r < 4; ++r)
                    qf[tt][ct][r] = (__bf16)acc[ct][tt][r];
    }
    __builtin_amdgcn_sched_barrier(0);   // acc reused: Q dead before K allocates

    // ---- Phase 1b: K GEMM (same accumulator block) ----
    {
        f32x4 acc[2][4];
#pragma unroll
        for (int ct = 0; ct < 2; ++ct) {
            f32x4 bk = *(const f32x4*)(bqkv + 256 + h * 32 + 16 * ct + 4 * g);
#pragma unroll
            for (int tt = 0; tt < 4; ++tt) acc[ct][tt] = bk;
        }
#pragma unroll
        for (int kc = 0; kc < 8; ++kc) {
            bf16x8 xf[4];
#pragma unroll
            for (int tt = 0; tt < 4; ++tt) {
                int row = 16 * tt + li; if (row > 48) row = 48;
                xf[tt] = ld8_lds(xw + row * 260 + kc * 32 + g * 8);
            }
#pragma unroll
            for (int ct = 0; ct < 2; ++ct) {
                bf16x8 ak = ld8_gb(wkb + ct * 4096 + kc * 512);
#pragma unroll
                for (int tt = 0; tt < 4; ++tt)
                    acc[ct][tt] = mfma_k32(ak, xf[tt], acc[ct][tt]);
            }
        }
#pragma unroll
        for (int ct = 0; ct < 2; ++ct)
#pragma unroll
            for (int tt = 0; tt < 4; ++tt)
#pragma unroll
                for (int r = 0; r < 4; ++r)
                    kf[tt][ct][r] = (__bf16)acc[ct][tt][r];
    }
    __builtin_amdgcn_sched_barrier(0);   // K acc dead before V allocates

    // ---- Phase 2: V GEMM (acc[tt][ct]: tok=16tt+4g+r, ch=16ct+li) ----
    bf16x4 vf[2][4];   // V^T frags [dt][kt]: row=li=d, k=4g+j=key
    {
        float bv0 = bqkv[512 + h * 32 + li];
        float bv1 = bqkv[512 + h * 32 + 16 + li];
        f32x4 va[4][2];
#pragma unroll
        for (int tt = 0; tt < 4; ++tt) {
            va[tt][0] = (f32x4){bv0, bv0, bv0, bv0};
            va[tt][1] = (f32x4){bv1, bv1, bv1, bv1};
        }
#pragma unroll
        for (int kc = 0; kc < 8; ++kc) {
            bf16x8 bvw0 = ld8_gb(wvb + kc * 512);
            bf16x8 bvw1 = ld8_gb(wvb + 4096 + kc * 512);
#pragma unroll
            for (int tt = 0; tt < 4; ++tt) {
                int row = 16 * tt + li; if (row > 48) row = 48;
                bf16x8 xf = ld8_lds(xw + row * 260 + kc * 32 + g * 8);
                va[tt][0] = mfma_k32(xf, bvw0, va[tt][0]);
                va[tt][1] = mfma_k32(xf, bvw1, va[tt][1]);
            }
        }
#pragma unroll
        for (int ct = 0; ct < 2; ++ct)
#pragma unroll
            for (int tt = 0; tt < 4; ++tt)
#pragma unroll
                for (int r = 0; r < 4; ++r)
                    vf[ct][tt][r] = (__bf16)va[tt][ct][r];
    }
    __builtin_amdgcn_sched_barrier(0);   // va dead before fused loop

    // ---- Phase 3: fused per-qt {S, exp2-softmax, PV, vector ctx store} ----
    const float* bmq = bm + cls * 32768 + h * 4096 + lane * 4;
#pragma unroll
    for (int qt = 0; qt < 4; ++qt) {
        f32x4 sv[4];   // S^T frags: lane holds key=16kt+4g+r, q=16qt+li
#pragma unroll
        for (int kt = 0; kt < 4; ++kt) {
            f32x4 acc = *(const f32x4*)(bmq + qt * 1024 + kt * 256);  // bias+mask (log2e)
            acc = mfma_k16(kf[kt][0], qf[qt][0], acc);
            acc = mfma_k16(kf[kt][1], qf[qt][1], acc);
            sv[kt] = acc;
        }
        float sum = 0.f;
#pragma unroll
        for (int kt = 0; kt < 4; ++kt)
#pragma unroll
            for (int r = 0; r < 4; ++r) {
                float e = exp2_hw(sv[kt][r]);   // no max-sub: |sv|<~25, masked -> 0
                sv[kt][r] = e;
                sum += e;
            }
        sum += __shfl_xor(sum, 16);
        sum += __shfl_xor(sum, 32);
        float inv = rcp_hw(sum);
        bf16x4 pp[4];  // unnormalized P frags: row=li=q, k=4g+j=key
#pragma unroll
        for (int kt = 0; kt < 4; ++kt)
#pragma unroll
            for (int r = 0; r < 4; ++r) pp[kt][r] = (__bf16)sv[kt][r];
        // PV swapped: A=vf -> d on 4g+r, B=pp -> q on li; inv is lane-local (q=li)
        const int q = 16 * qt + li;
#pragma unroll
        for (int dt = 0; dt < 2; ++dt) {
            f32x4 acc = zf;
#pragma unroll
            for (int kt = 0; kt < 4; ++kt)
                acc = mfma_k16(vf[dt][kt], pp[kt], acc);
            acc *= inv;
            bf16x4 o4 = pk4(acc);
            if (q < 49)
                *(bf16x4*)(cb + q * 260 + 32 * h + 16 * dt + 4 * g) = o4;
        }
    }
    __syncthreads();   // barrier #2 (ctx complete)

    // ---- proj: 8 waves, wave = (pm: 32 rows, pn: 64 cols) ----
    // swapped: A=wp rows -> o on 4g+r, B=cb rows -> tok on li
    const int pm = wid >> 2, pn = wid & 3;
    const __bf16* wpb = wb + (size_t)(48 + 4 * pn) * 4096 + lane * 8;

    f32x4 pacc[2][4];
#pragma unroll
    for (int nt = 0; nt < 4; ++nt) {
        f32x4 pb = *(const f32x4*)(pbias + 64 * pn + 16 * nt + 4 * g);
        pacc[0][nt] = pb;
        pacc[1][nt] = pb;
    }

#pragma unroll
    for (int kc = 0; kc < 8; ++kc) {
        bf16x8 a[2];
#pragma unroll
        for (int mt = 0; mt < 2; ++mt) {
            int row = 32 * pm + 16 * mt + li; if (row > 48) row = 48;
            a[mt] = ld8_lds(cb + row * 260 + kc * 32 + g * 8);
        }
#pragma unroll
        for (int nt = 0; nt < 4; ++nt) {
            bf16x8 bb = ld8_gb(wpb + nt * 4096 + kc * 512);
#pragma unroll
            for (int mt = 0; mt < 2; ++mt)
                pacc[mt][nt] = mfma_k32(bb, a[mt], pacc[mt][nt]);
        }
    }

    // ---- epilogue: vector fp32 scatter via obase LUT (bias pre-initialized) ----
#pragma unroll
    for (int mt = 0; mt < 2; ++mt) {
        int tok = 32 * pm + 16 * mt + li;
        if (tok < 49) {
            float* op = out + obase[tok] + 64 * pn + 4 * g;
#pragma unroll
            for (int nt = 0; nt < 4; ++nt)
                *(f32x4*)(op + 16 * nt) = pacc[mt][nt];
        }
    }
}

extern "C" void kernel_launch(void* const* d_in, const int* in_sizes, int n_in,
                              void* d_out, int out_size, void* d_ws, size_t ws_size,
                              hipStream_t stream) {
    const float* x    = (const float*)d_in[0];
    const float* wqkv = (const float*)d_in[1];
    const float* bqkv = (const float*)d_in[2];
    const float* wp   = (const float*)d_in[3];
    const float* pb   = (const float*)d_in[4];
    const float* btab = (const float*)d_in[5];
    float* out = (float*)d_out;

    __bf16* wbuf = (__bf16*)d_ws;                       // 512 KB weights (bf16)
    float* bm = (float*)((char*)d_ws + 524288);         // 512 KB bias+mask table
    k_pre<<<640, 256, 0, stream>>>(wqkv, wp, btab, wbuf, bm);
    k_swin<<<2048, 512, 0, stream>>>(x, wbuf, bqkv, bm, pb, out);
}